// Round 1
// baseline (329.304 us; speedup 1.0000x reference)
//
#include <hip/hip_runtime.h>
#include <hip/hip_bf16.h>

// out[b, n, d] = (n == 0 ? x_class[d] : inputs[b, n-1, d]) + embeddings[n, d]
// B=64, N=1024 (so out rows per batch = 1025), D=768.
// Pure streaming op -> memory-bound. float4 everywhere; D=768 = 192 float4.
// Grid (1025, 64): blockIdx.x = n (position), blockIdx.y = b (batch).
// Block = 192 threads, one float4 per thread, one output row per block.
// The n==0 branch is block-uniform (no divergence).

#define D4 192           // 768 / 4
#define NP1 1025         // N + 1

__global__ __launch_bounds__(192)
void pos_embed_kernel(const float4* __restrict__ in4,    // [64*1024*192]
                      const float4* __restrict__ cls4,   // [192]
                      const float4* __restrict__ emb4,   // [1025*192]
                      float4* __restrict__ out4) {       // [64*1025*192]
    const int n  = blockIdx.x;    // 0..1024
    const int b  = blockIdx.y;    // 0..63
    const int d4 = threadIdx.x;   // 0..191

    float4 e = emb4[n * D4 + d4];
    float4 s;
    if (n == 0) {
        s = cls4[d4];
    } else {
        s = in4[(b * 1024 + (n - 1)) * D4 + d4];
    }
    float4 r;
    r.x = s.x + e.x;
    r.y = s.y + e.y;
    r.z = s.z + e.z;
    r.w = s.w + e.w;
    out4[(b * NP1 + n) * D4 + d4] = r;
}

extern "C" void kernel_launch(void* const* d_in, const int* in_sizes, int n_in,
                              void* d_out, int out_size, void* d_ws, size_t ws_size,
                              hipStream_t stream) {
    const float4* in4  = (const float4*)d_in[0];  // inputs [64,1024,768]
    const float4* cls4 = (const float4*)d_in[1];  // x_class [768]
    const float4* emb4 = (const float4*)d_in[2];  // embeddings [1025,768]
    float4* out4       = (float4*)d_out;          // [64,1025,768]

    dim3 grid(NP1, 64, 1);
    dim3 block(D4, 1, 1);
    pos_embed_kernel<<<grid, block, 0, stream>>>(in4, cls4, emb4, out4);
}

// Round 3
// 327.961 us; speedup vs baseline: 1.0041x; 1.0041x over previous
//
#include <hip/hip_runtime.h>
#include <hip/hip_bf16.h>

// out[b, n, d] = (n == 0 ? x_class[d] : inputs[b, n-1, d]) + embeddings[n, d]
// B=64, N=1024, D=768. Pure streaming triad, memory-bound (~406 MB -> ~64 us floor).
//
// Key structure: for fixed b, the n>=1 bulk is CONTIGUOUS in all three arrays:
//   out4[b*196800 + 192 + i] = in4[b*196608 + i] + emb4[192 + i],  i in [0, 196608)
// (float4 units; 196800 = 1025*192, 196608 = 1024*192). No per-element index math.
// 196608 = 48 * 256 * 16 exactly -> grid.x = 48 bulk blocks (+1 cls block) per b,
// 256 threads, 16 fully-unrolled iterations, zero tail.
//
// Nontemporal on in/out (touched exactly once) keeps L2 for the 64x-reused emb table.
// NOTE: nontemporal builtins need a native clang ext-vector type, not HIP_vector_type.

typedef float f4 __attribute__((ext_vector_type(4)));

#define D4      192      // 768 / 4
#define ROWS4   196800   // 1025 * 192  (per-b out stride, float4 units)
#define BULK4   196608   // 1024 * 192  (per-b in stride / bulk count, float4 units)
#define BLKS    48       // bulk blocks per b
#define STRIDE  (BLKS * 256)   // 12288
#define ITERS   16       // BULK4 / STRIDE

__global__ __launch_bounds__(256)
void pos_embed_kernel(const f4* __restrict__ in4,    // [64*196608]
                      const f4* __restrict__ cls4,   // [192]
                      const f4* __restrict__ emb4,   // [1025*192]
                      f4* __restrict__ out4) {       // [64*196800]
    const int b = blockIdx.y;
    const f4* __restrict__ inb  = in4  + (size_t)b * BULK4;
    f4* __restrict__       outb = out4 + (size_t)b * ROWS4;

    if (blockIdx.x == BLKS) {
        // cls row: out[b,0,:] = x_class + emb[0,:]
        const int t = threadIdx.x;
        if (t < D4) {
            outb[t] = cls4[t] + emb4[t];
        }
        return;
    }

    int i = blockIdx.x * 256 + threadIdx.x;   // 0 .. STRIDE-1
    #pragma unroll
    for (int k = 0; k < ITERS; ++k, i += STRIDE) {
        f4 s = __builtin_nontemporal_load(&inb[i]);
        f4 e = emb4[D4 + i];              // cached: reused across all 64 b
        f4 r = s + e;
        __builtin_nontemporal_store(r, &outb[D4 + i]);
    }
}

extern "C" void kernel_launch(void* const* d_in, const int* in_sizes, int n_in,
                              void* d_out, int out_size, void* d_ws, size_t ws_size,
                              hipStream_t stream) {
    const f4* in4  = (const f4*)d_in[0];  // inputs [64,1024,768]
    const f4* cls4 = (const f4*)d_in[1];  // x_class [768]
    const f4* emb4 = (const f4*)d_in[2];  // embeddings [1025,768]
    f4* out4       = (f4*)d_out;          // [64,1025,768]

    dim3 grid(BLKS + 1, 64, 1);
    dim3 block(256, 1, 1);
    pos_embed_kernel<<<grid, block, 0, stream>>>(in4, cls4, emb4, out4);
}